// Round 2
// baseline (1505.118 us; speedup 1.0000x reference)
//
#include <hip/hip_runtime.h>
#include <stdint.h>

#define NN 50000      // nodes
#define NRELS 3       // relations
#define NE 800000     // edges per relation
#define DIN 300
#define DH 256
#define NCHUNK 196    // ceil(NN/256)

typedef __attribute__((ext_vector_type(8))) short bf16x8;
typedef __attribute__((ext_vector_type(4))) float f32x4;

__device__ __forceinline__ float bf2f(unsigned short u){
    union { unsigned int i; float f; } v; v.i = ((unsigned int)u) << 16; return v.f;
}
__device__ __forceinline__ unsigned short f2bf(float f){
    union { float f; unsigned int i; } v; v.f = f;
    return (unsigned short)((v.i + 0x7FFFu + ((v.i >> 16) & 1u)) >> 16);
}

// ---------------- attention softmax (6 scalars) ----------------
__global__ void k_att(const float* __restrict__ a_att, const float* __restrict__ r_att,
                      float* __restrict__ att){
    if (threadIdx.x == 0){
        float m = fmaxf(a_att[0], fmaxf(a_att[1], a_att[2]));
        float e0 = expf(a_att[0]-m), e1 = expf(a_att[1]-m), e2 = expf(a_att[2]-m);
        float s = e0+e1+e2;
        att[0]=e0/s; att[1]=e1/s; att[2]=e2/s;
        m = fmaxf(r_att[0], fmaxf(r_att[1], r_att[2]));
        e0 = expf(r_att[0]-m); e1 = expf(r_att[1]-m); e2 = expf(r_att[2]-m);
        s = e0+e1+e2;
        att[3]=e0/s; att[4]=e1/s; att[5]=e2/s;
    }
}

// ---------------- CSR build: histogram ----------------
__global__ void k_hist(const int* __restrict__ src, const int* __restrict__ dst,
                       int* __restrict__ counts){
    int rel = blockIdx.y;
    int e = blockIdx.x*256 + threadIdx.x;
    if (e >= NE) return;
    int d = dst[(size_t)rel*NE + e];
    int s = src[(size_t)rel*NE + e];
    atomicAdd(&counts[rel*NN + d], 1);           // layer1 rows = dst
    atomicAdd(&counts[(NRELS+rel)*NN + s], 1);   // layer2 rows = src
}

// ---------------- CSR build: two-level exclusive scan ----------------
__global__ void k_scanA(const int* __restrict__ counts, int* __restrict__ partials){
    __shared__ int lds[256];
    int a = blockIdx.y;
    int idx = blockIdx.x*256 + threadIdx.x;
    int v = (idx < NN) ? counts[a*NN + idx] : 0;
    lds[threadIdx.x] = v; __syncthreads();
    for (int off = 128; off > 0; off >>= 1){
        if (threadIdx.x < off) lds[threadIdx.x] += lds[threadIdx.x + off];
        __syncthreads();
    }
    if (threadIdx.x == 0) partials[a*NCHUNK + blockIdx.x] = lds[0];
}

__global__ void k_scanB(int* __restrict__ partials){
    __shared__ int lds[256];
    for (int a = 0; a < 6; ++a){
        int v = (threadIdx.x < NCHUNK) ? partials[a*NCHUNK + threadIdx.x] : 0;
        lds[threadIdx.x] = v; __syncthreads();
        for (int off = 1; off < 256; off <<= 1){
            int t = (threadIdx.x >= off) ? lds[threadIdx.x - off] : 0;
            __syncthreads();
            lds[threadIdx.x] += t;
            __syncthreads();
        }
        int incl = lds[threadIdx.x];
        if (threadIdx.x < NCHUNK) partials[a*NCHUNK + threadIdx.x] = incl - v; // exclusive
        __syncthreads();
    }
}

__global__ void k_scanC(const int* __restrict__ counts, const int* __restrict__ partials,
                        int* __restrict__ row_start, int* __restrict__ cursor){
    __shared__ int lds[256];
    int a = blockIdx.y;
    int idx = blockIdx.x*256 + threadIdx.x;
    int v = (idx < NN) ? counts[a*NN + idx] : 0;
    lds[threadIdx.x] = v; __syncthreads();
    for (int off = 1; off < 256; off <<= 1){
        int t = (threadIdx.x >= off) ? lds[threadIdx.x - off] : 0;
        __syncthreads();
        lds[threadIdx.x] += t;
        __syncthreads();
    }
    int excl = lds[threadIdx.x] - v + partials[a*NCHUNK + blockIdx.x];
    if (idx < NN){
        row_start[a*(NN+1) + idx] = excl;
        cursor[a*NN + idx] = excl;   // cursor starts at row base -> atomicAdd gives absolute slot
    }
    if (idx == NN-1) row_start[a*(NN+1) + NN] = excl + v;
}

// ---------------- CSR build: scatter sorted col ----------------
__global__ void k_scatter(const int* __restrict__ src, const int* __restrict__ dst,
                          int* __restrict__ cursor, int* __restrict__ colS){
    int rel = blockIdx.y;
    int e = blockIdx.x*256 + threadIdx.x;
    if (e >= NE) return;
    int s = src[(size_t)rel*NE + e];
    int d = dst[(size_t)rel*NE + e];
    {   // layer1: row=dst, col=src
        int slot = atomicAdd(&cursor[rel*NN + d], 1);
        colS[(size_t)rel*NE + slot] = s;
    }
    {   // layer2: row=src, col=dst
        int a = NRELS + rel;
        int slot = atomicAdd(&cursor[a*NN + s], 1);
        colS[(size_t)a*NE + slot] = d;
    }
}

// ---------------- GEMM1: f32 VALU, out[m][n] = A@W + b, bf16 out ----------------
template<int K, int BK>
__global__ __launch_bounds__(256) void k_gemm(const float* __restrict__ A,
                                              const float* __restrict__ W,
                                              const float* __restrict__ bias,
                                              unsigned short* __restrict__ out, int M){
    constexpr int BM = 32;
    __shared__ float ldsW[BK*DH];
    __shared__ float ldsX[BM*BK];
    const int tid = threadIdx.x;
    const int row0 = blockIdx.x * BM;
    const int jc = tid & 63;       // column group: cols jc*4 .. jc*4+3
    const int rg = tid >> 6;       // row group: rows rg*8 .. rg*8+7
    float acc[8][4] = {};
    for (int k0 = 0; k0 < K; k0 += BK){
        for (int idx = tid; idx < BK*DH; idx += 256)
            ldsW[idx] = W[(size_t)k0*DH + idx];
        for (int idx = tid; idx < BM*BK; idx += 256){
            int r = idx / BK, k = idx % BK;
            int row = row0 + r;
            ldsX[idx] = (row < M) ? A[(size_t)row*K + k0 + k] : 0.f;
        }
        __syncthreads();
        for (int k = 0; k < BK; ++k){
            const float4 wv = *(const float4*)(&ldsW[k*DH + jc*4]);
            #pragma unroll
            for (int r = 0; r < 8; ++r){
                float xv = ldsX[(rg*8 + r)*BK + k];
                acc[r][0] += xv*wv.x; acc[r][1] += xv*wv.y;
                acc[r][2] += xv*wv.z; acc[r][3] += xv*wv.w;
            }
        }
        __syncthreads();
    }
    const float4 bv = *(const float4*)(&bias[jc*4]);
    #pragma unroll
    for (int r = 0; r < 8; ++r){
        int row = row0 + rg*8 + r;
        if (row < M){
            ushort4 o;
            o.x = f2bf(acc[r][0] + bv.x);
            o.y = f2bf(acc[r][1] + bv.y);
            o.z = f2bf(acc[r][2] + bv.z);
            o.w = f2bf(acc[r][3] + bv.w);
            *(ushort4*)(&out[(size_t)row*DH + jc*4]) = o;
        }
    }
}

// ---------------- w2 transpose + bf16 convert: w2t[n][k] ----------------
__global__ void k_w2t(const float* __restrict__ w2, unsigned short* __restrict__ w2t){
    int idx = blockIdx.x*256 + threadIdx.x;   // idx over [n][k], 65536
    int n = idx >> 8, k = idx & 255;
    w2t[idx] = f2bf(w2[k*DH + n]);
}

// ---------------- GEMM2: bf16 MFMA 16x16x32; A=h (m,k), B=w2t (n,k) ----------------
__global__ __launch_bounds__(256) void k_gemm2(const unsigned short* __restrict__ h,
                                               const unsigned short* __restrict__ w2t,
                                               const float* __restrict__ bias,
                                               unsigned short* __restrict__ out, int M){
    const int wave = threadIdx.x >> 6;
    const int lane = threadIdx.x & 63;
    const int row0 = (blockIdx.x*4 + wave) * 16;
    if (row0 >= M) return;
    const int r = lane & 15;      // A row / B col within 16
    const int g = lane >> 4;      // k-group (g*8 .. g*8+7)
    f32x4 acc[16];
    #pragma unroll
    for (int n = 0; n < 16; ++n) acc[n] = (f32x4){0.f,0.f,0.f,0.f};
    #pragma unroll
    for (int kk = 0; kk < DH/32; ++kk){
        const int k0 = kk*32;
        bf16x8 a = *(const bf16x8*)(h + (size_t)(row0 + r)*DH + k0 + g*8);
        #pragma unroll
        for (int n = 0; n < 16; ++n){
            bf16x8 b = *(const bf16x8*)(w2t + (size_t)(n*16 + r)*DH + k0 + g*8);
            acc[n] = __builtin_amdgcn_mfma_f32_16x16x32_bf16(a, b, acc[n], 0, 0, 0);
        }
    }
    #pragma unroll
    for (int n = 0; n < 16; ++n){
        float bv = bias[n*16 + r];
        #pragma unroll
        for (int j = 0; j < 4; ++j){
            int row = row0 + g*4 + j;   // C: col=lane&15, row=(lane>>4)*4+reg
            out[(size_t)row*DH + n*16 + r] = f2bf(acc[n][j] + bv);
        }
    }
}

// ---------------- SPMM layer1 (gather by dst-CSR, fused LeakyReLU) ----------------
__global__ __launch_bounds__(256) void k_spmm1(const unsigned short* __restrict__ feat,
                                               const int* __restrict__ row_start,
                                               const int* __restrict__ colS,
                                               const float* __restrict__ att,
                                               unsigned short* __restrict__ out){
    int row = blockIdx.x*4 + (threadIdx.x >> 6);
    int lane = threadIdx.x & 63;
    if (row >= NN) return;
    float a0=0.f, a1=0.f, a2=0.f, a3=0.f;
    #pragma unroll
    for (int i = 0; i < NRELS; ++i){
        const int s0 = row_start[i*(NN+1) + row];
        const int s1 = row_start[i*(NN+1) + row + 1];
        if (s1 > s0){
            const int* cp = colS + (size_t)i*NE;
            float t0=0.f, t1=0.f, t2=0.f, t3=0.f;
            for (int slot = s0; slot < s1; ++slot){
                int c = cp[slot];
                ushort4 u = *(const ushort4*)(feat + (size_t)c*DH + lane*4);
                t0 += bf2f(u.x); t1 += bf2f(u.y); t2 += bf2f(u.z); t3 += bf2f(u.w);
            }
            float v = att[i] / (float)(s1 - s0);   // = att[i] * (1/indeg)
            a0 += v*t0; a1 += v*t1; a2 += v*t2; a3 += v*t3;
        }
    }
    // LeakyReLU(0.2)
    a0 = a0 > 0.f ? a0 : 0.2f*a0;
    a1 = a1 > 0.f ? a1 : 0.2f*a1;
    a2 = a2 > 0.f ? a2 : 0.2f*a2;
    a3 = a3 > 0.f ? a3 : 0.2f*a3;
    ushort4 o; o.x = f2bf(a0); o.y = f2bf(a1); o.z = f2bf(a2); o.w = f2bf(a3);
    *(ushort4*)(&out[(size_t)row*DH + lane*4]) = o;
}

// ---------------- SPMM layer2 (gather by src-CSR, fused L2 normalize) ----------------
__global__ __launch_bounds__(256) void k_spmm2(const unsigned short* __restrict__ feat,
                                               const int* __restrict__ row_start,
                                               const int* __restrict__ colS,
                                               const float* __restrict__ att,
                                               float* __restrict__ out){
    int row = blockIdx.x*4 + (threadIdx.x >> 6);
    int lane = threadIdx.x & 63;
    if (row >= NN) return;
    float a0=0.f, a1=0.f, a2=0.f, a3=0.f;
    #pragma unroll
    for (int i = 0; i < NRELS; ++i){
        const int a = NRELS + i;
        const int s0 = row_start[a*(NN+1) + row];
        const int s1 = row_start[a*(NN+1) + row + 1];
        if (s1 > s0){
            const int* cp = colS + (size_t)a*NE;
            float t0=0.f, t1=0.f, t2=0.f, t3=0.f;
            for (int slot = s0; slot < s1; ++slot){
                int c = cp[slot];
                ushort4 u = *(const ushort4*)(feat + (size_t)c*DH + lane*4);
                t0 += bf2f(u.x); t1 += bf2f(u.y); t2 += bf2f(u.z); t3 += bf2f(u.w);
            }
            float v = att[a] / (float)(s1 - s0);   // = att2[i] * (1/outdeg)
            a0 += v*t0; a1 += v*t1; a2 += v*t2; a3 += v*t3;
        }
    }
    float ss = a0*a0 + a1*a1 + a2*a2 + a3*a3;
    #pragma unroll
    for (int off = 32; off > 0; off >>= 1) ss += __shfl_xor(ss, off);
    float scale = 1.0f / fmaxf(sqrtf(ss), 1e-12f);
    float4 o; o.x = a0*scale; o.y = a1*scale; o.z = a2*scale; o.w = a3*scale;
    *(float4*)(&out[(size_t)row*DH + lane*4]) = o;
}

extern "C" void kernel_launch(void* const* d_in, const int* in_sizes, int n_in,
                              void* d_out, int out_size, void* d_ws, size_t ws_size,
                              hipStream_t stream){
    const float* x      = (const float*)d_in[0];
    const float* w1     = (const float*)d_in[1];
    const float* b1     = (const float*)d_in[2];
    const float* w2     = (const float*)d_in[3];
    const float* b2     = (const float*)d_in[4];
    const float* a_att  = (const float*)d_in[5];
    const float* r_att  = (const float*)d_in[6];
    const int*   src    = (const int*)d_in[7];
    const int*   dst    = (const int*)d_in[8];
    float* out = (float*)d_out;

    char* ws = (char*)d_ws;
    size_t off = 0;
    auto take = [&](size_t bytes)->char*{
        char* p = ws + off;
        off = (off + bytes + 255) & ~(size_t)255;
        return p;
    };
    float*          att       = (float*)take(6*sizeof(float));
    unsigned short* sbuf      = (unsigned short*)take((size_t)NN*DH*2); // s, later s2
    unsigned short* hbuf      = (unsigned short*)take((size_t)NN*DH*2); // h
    unsigned short* w2t       = (unsigned short*)take((size_t)DH*DH*2);
    int*            counts    = (int*)take((size_t)6*NN*4);
    int*            cursor    = (int*)take((size_t)6*NN*4);
    int*            row_start = (int*)take((size_t)6*(NN+1)*4);
    int*            partials  = (int*)take((size_t)6*NCHUNK*4);
    int*            colS      = (int*)take((size_t)6*NE*4);
    (void)ws_size; (void)in_sizes; (void)n_in; (void)out_size;

    hipMemsetAsync(counts, 0, (size_t)6*NN*4, stream);

    k_att<<<1, 64, 0, stream>>>(a_att, r_att, att);
    k_w2t<<<(DH*DH + 255)/256, 256, 0, stream>>>(w2, w2t);

    dim3 egrid((NE + 255)/256, NRELS);
    k_hist<<<egrid, 256, 0, stream>>>(src, dst, counts);
    k_scanA<<<dim3(NCHUNK, 6), 256, 0, stream>>>(counts, partials);
    k_scanB<<<1, 256, 0, stream>>>(partials);
    k_scanC<<<dim3(NCHUNK, 6), 256, 0, stream>>>(counts, partials, row_start, cursor);
    k_scatter<<<egrid, 256, 0, stream>>>(src, dst, cursor, colS);

    // layer 1: s = x@w1+b1 ; h = leaky(sum_i att[i]*spmm_i(s))
    k_gemm<DIN, 50><<<(NN + 31)/32, 256, 0, stream>>>(x, w1, b1, sbuf, NN);
    k_spmm1<<<(NN + 3)/4, 256, 0, stream>>>(sbuf, row_start, colS, att, hbuf);

    // layer 2: s2 = h@w2+b2 (MFMA, reuse sbuf) ; out = normalize(sum att2*spmm(s2))
    k_gemm2<<<(NN/16 + 3)/4, 256, 0, stream>>>(hbuf, w2t, b2, sbuf, NN);
    k_spmm2<<<(NN + 3)/4, 256, 0, stream>>>(sbuf, row_start, colS, att, out);
}